// Round 13
// baseline (768.319 us; speedup 1.0000x reference)
//
#include <hip/hip_runtime.h>
#include <math.h>

// Problem sizes
// B=16, L=1024, DIN=64, H=256, N=64, TEMB=128, NB=6; chunk T=64, C=16

typedef __attribute__((ext_vector_type(8))) short bf16x8;
typedef __attribute__((ext_vector_type(4))) float f32x4;

__device__ __forceinline__ short f2bf(float f) {
  unsigned u = __builtin_bit_cast(unsigned, f);
  unsigned r = (u + 0x7FFFu + ((u >> 16) & 1u)) >> 16;
  return (short)r;
}
__device__ __forceinline__ float bf2f(unsigned short v) {
  unsigned u = ((unsigned)v) << 16;
  return __builtin_bit_cast(float, u);
}
__device__ __forceinline__ float gelu_f(float v) {
  // tanh-form gelu via sigmoid: v * sigmoid(2*0.7978845608*(v + 0.044715 v^3)); max err ~3e-4
  float q = 1.5957691216f * v * fmaf(0.044715f, v * v, 1.f);
  return v / (1.f + __expf(-q));
}

// ---------------- t-embedding MLP:  tv[b,h] ----------------
__global__ __launch_bounds__(256) void k_temb(
    const float* __restrict__ t, const float* __restrict__ Wt1, const float* __restrict__ bt1,
    const float* __restrict__ Wt2, const float* __restrict__ bt2, float* __restrict__ tv) {
  int b = blockIdx.x, tid = threadIdx.x;
  __shared__ float emb[128];
  __shared__ float tv1[256];
  if (tid < 128) {
    int j = tid & 63;
    float f = expf(-logf(10000.f) / 63.f * (float)j);
    float a = t[b] * f;
    emb[tid] = (tid < 64) ? sinf(a) : cosf(a);
  }
  __syncthreads();
  float acc = bt1[tid];
  for (int k = 0; k < 128; k++) acc = fmaf(emb[k], Wt1[k * 256 + tid], acc);
  tv1[tid] = acc / (1.f + expf(-acc));
  __syncthreads();
  float acc2 = bt2[tid];
  for (int k = 0; k < 256; k++) acc2 = fmaf(tv1[k], Wt2[k * 256 + tid], acc2);
  tv[b * 256 + tid] = acc2 / (1.f + expf(-acc2));
}

// ---------------- tt_all[i,b,h] = tv[b]@tW[i] + tb[i] ----------------
__global__ __launch_bounds__(256) void k_tt(
    const float* __restrict__ tv, const float* __restrict__ tW, const float* __restrict__ tb,
    float* __restrict__ tt_all) {
  int i = blockIdx.x, b = blockIdx.y, h = threadIdx.x;
  __shared__ float s[256];
  s[h] = tv[b * 256 + h];
  __syncthreads();
  const float* W = tW + i * 256 * 256;
  float acc = tb[i * 256 + h];
  for (int k = 0; k < 256; k++) acc = fmaf(s[k], W[k * 256 + h], acc);
  tt_all[(i * 16 + b) * 256 + h] = acc;
}

// ---------------- input proj: xbf[b,h,l] = relu(input@W_in + b_in), transposed, bf16 ----------------
__global__ __launch_bounds__(256) void k_in(
    const float* __restrict__ inp, const float* __restrict__ W, const float* __restrict__ bias,
    unsigned short* __restrict__ xbf) {
  int lt = blockIdx.x, b = blockIdx.y, h = threadIdx.x;
  __shared__ float si[64][68];
  int l0 = lt * 64;
  for (int rep = 0; rep < 16; rep++) {
    int idx = rep * 256 + h;
    int l = idx >> 6, d = idx & 63;
    si[l][d] = inp[(size_t)(b * 1024 + l0 + l) * 64 + d];
  }
  float wc[64];
  #pragma unroll
  for (int d = 0; d < 64; d++) wc[d] = W[d * 256 + h];
  float bh = bias[h];
  __syncthreads();
  unsigned short* xp = xbf + (size_t)(b * 256 + h) * 1024 + l0;
  for (int l4 = 0; l4 < 16; l4++) {
    float op[4];
    #pragma unroll
    for (int j = 0; j < 4; j++) {
      int l = l4 * 4 + j;
      float a = bh;
      #pragma unroll
      for (int d4 = 0; d4 < 16; d4++) {
        float4 v = *reinterpret_cast<const float4*>(&si[l][d4 * 4]);
        a = fmaf(v.x, wc[d4 * 4 + 0], a);
        a = fmaf(v.y, wc[d4 * 4 + 1], a);
        a = fmaf(v.z, wc[d4 * 4 + 2], a);
        a = fmaf(v.w, wc[d4 * 4 + 3], a);
      }
      op[j] = fmaxf(a, 0.f);
    }
    ushort4 o = make_ushort4((unsigned short)f2bf(op[0]), (unsigned short)f2bf(op[1]),
                             (unsigned short)f2bf(op[2]), (unsigned short)f2bf(op[3]));
    *reinterpret_cast<ushort4*>(xp + l4 * 4) = o;
  }
}

// ---------------- per-mode tables: w, w^64, dC (all blocks) ----------------
__global__ __launch_bounds__(256) void k_tab(
    const float* __restrict__ log_dt, const float* __restrict__ A_log_re, const float* __restrict__ A_im,
    const float* __restrict__ C_re, const float* __restrict__ C_im,
    float* __restrict__ wtab, float* __restrict__ wTtab, float* __restrict__ dCtab) {
  int idx = blockIdx.x * 256 + threadIdx.x;  // over NB*H*N = 98304
  int i = idx / (256 * 64);
  int rem = idx % (256 * 64);
  int h = rem >> 6, n = rem & 63;
  float dt = expf(log_dt[i * 256 + h]);
  float Ar = -expf(A_log_re[idx]);
  float Ai = A_im[idx];
  float ar = dt * Ar, ai = dt * Ai;
  float ea = expf(ar);
  float wr = ea * cosf(ai), wi = ea * sinf(ai);
  float pr = wr, pi = wi;
  #pragma unroll
  for (int s = 0; s < 6; s++) { float nr = pr * pr - pi * pi; float ni = 2.f * pr * pi; pr = nr; pi = ni; }
  float den = Ar * Ar + Ai * Ai;
  float qr = ((wr - 1.f) * Ar + wi * Ai) / den;
  float qi = (wi * Ar - (wr - 1.f) * Ai) / den;
  wtab[idx * 2] = wr; wtab[idx * 2 + 1] = wi;
  wTtab[idx * 2] = pr; wTtab[idx * 2 + 1] = pi;
  #pragma unroll
  for (int s = 0; s < 2; s++) {
    float cr = C_re[((size_t)(i * 2 + s) * 256 + h) * 64 + n];
    float ci = C_im[((size_t)(i * 2 + s) * 256 + h) * 64 + n];
    dCtab[(((size_t)(i * 2 + s) * 256 + h) * 64 + n) * 2]     = cr * qr - ci * qi;
    dCtab[(((size_t)(i * 2 + s) * 256 + h) * 64 + n) * 2 + 1] = cr * qi + ci * qr;
  }
}

// ---------------- weight prep: bf16 conversions ----------------
__global__ __launch_bounds__(256) void k_prep(
    const float* __restrict__ s4W, const float* __restrict__ c1W, const float* __restrict__ c2W,
    const float* __restrict__ Wo1,
    unsigned short* __restrict__ s4Wbf, unsigned short* __restrict__ c12Wbf, unsigned short* __restrict__ Wo1T) {
  int idx = blockIdx.x * 256 + threadIdx.x;  // 4864*256 = 1245184
  if (idx < 393216) {
    s4Wbf[idx] = (unsigned short)f2bf(s4W[idx]);
  } else if (idx < 393216 + 786432) {
    int j = idx - 393216;
    int i = j / 131072, r = j % 131072;
    int o2 = r >> 8, k = r & 255;
    float v = (o2 < 256) ? c1W[(size_t)i * 65536 + o2 * 256 + k]
                         : c2W[(size_t)i * 65536 + (o2 - 256) * 256 + k];
    c12Wbf[j] = (unsigned short)f2bf(v);
  } else {
    int j = idx - 1179648;  // < 65536
    int o = j >> 8, k = j & 255;
    Wo1T[j] = (unsigned short)f2bf(Wo1[k * 256 + o]);
  }
}

// ---------------- Ptb[i][h][t][2n{+1}] = bf16 {Re, -Im}(w^t), all blocks ----------------
__global__ __launch_bounds__(256) void k_pcar(const float* __restrict__ wtab, unsigned short* __restrict__ Ptb) {
  int idx = blockIdx.x * 256 + threadIdx.x;  // i*16384 + h*64 + n, 98304
  int i = idx >> 14, h = (idx >> 6) & 255, n = idx & 63;
  float wr = wtab[idx * 2], wi = wtab[idx * 2 + 1];
  float pr = 1.f, pi = 0.f;
  unsigned short* base = Ptb + (size_t)i * 2097152 + (size_t)h * 8192 + 2 * n;
  for (int t = 0; t < 64; t++) {
    *reinterpret_cast<ushort2*>(base + t * 128) =
        make_ushort2((unsigned short)f2bf(pr), (unsigned short)f2bf(-pi));
    float nr2 = pr * wr - pi * wi, ni2 = pr * wi + pi * wr;
    pr = nr2; pi = ni2;
  }
}

// ---------------- Ktap_all[i][s][h][j] = 2 Re(sum_n dC_s w^j) ----------------
__global__ __launch_bounds__(256) void k_ktap(
    const float* __restrict__ dCtab, const unsigned short* __restrict__ Ptb, float* __restrict__ Ktap) {
  int idx = blockIdx.x * 256 + threadIdx.x;  // ((i*2+s)*256+h)*64+j, 196608
  int j = idx & 63;
  int h = (idx >> 6) & 255;
  int i = idx >> 15;
  const float* dc = dCtab + (size_t)(idx >> 6) * 128;
  const unsigned short* P = Ptb + (size_t)i * 2097152 + (size_t)h * 8192 + j * 128;
  float acc = 0.f;
  for (int q = 0; q < 32; q++) {
    float4 d = *reinterpret_cast<const float4*>(dc + q * 4);
    ushort4 p = *reinterpret_cast<const ushort4*>(P + q * 4);
    acc = fmaf(d.x, bf2f(p.x), fmaf(d.y, bf2f(p.y), fmaf(d.z, bf2f(p.z), fmaf(d.w, bf2f(p.w), acc))));
  }
  Ktap[idx] = 2.f * acc;
}

// ---------------- LayerNorm over H with +tt, xbf -> zn bf16 ----------------
__global__ __launch_bounds__(256) void k_ln(
    const unsigned short* __restrict__ xbf, const float* __restrict__ tt_all,
    const float* __restrict__ g, const float* __restrict__ bta, unsigned short* __restrict__ znbf, int i) {
  int ct = blockIdx.x, b = blockIdx.y, tid = threadIdx.x;
  __shared__ unsigned short tile[64][266];
  __shared__ float stt[256];
  __shared__ float red[8][64];
  __shared__ float mu_s[64], rs_s[64];
  stt[tid] = tt_all[(i * 16 + b) * 256 + tid];
  __syncthreads();
  int l0 = ct * 64;
  const unsigned short* xb = xbf + (size_t)(b * 256) * 1024 + l0;
  for (int rep = 0; rep < 16; rep++) {
    int idx = rep * 256 + tid;
    int h = idx >> 4;
    int l4 = (idx & 15) * 4;
    ushort4 v = *reinterpret_cast<const ushort4*>(xb + (size_t)h * 1024 + l4);
    float a = stt[h];
    tile[l4][h]     = (unsigned short)f2bf(bf2f(v.x) + a);
    tile[l4 + 1][h] = (unsigned short)f2bf(bf2f(v.y) + a);
    tile[l4 + 2][h] = (unsigned short)f2bf(bf2f(v.z) + a);
    tile[l4 + 3][h] = (unsigned short)f2bf(bf2f(v.w) + a);
  }
  __syncthreads();
  int l = tid & 63, part = tid >> 6;
  float s1 = 0.f, s2 = 0.f;
  for (int k2 = 0; k2 < 32; k2++) {
    ushort2 v2 = *reinterpret_cast<const ushort2*>(&tile[l][part * 64 + k2 * 2]);
    float a = bf2f(v2.x), bq = bf2f(v2.y);
    s1 += a + bq;
    s2 = fmaf(a, a, fmaf(bq, bq, s2));
  }
  red[part][l] = s1; red[4 + part][l] = s2;
  __syncthreads();
  if (tid < 64) {
    float a = red[0][tid] + red[1][tid] + red[2][tid] + red[3][tid];
    float q = red[4][tid] + red[5][tid] + red[6][tid] + red[7][tid];
    float mu = a * (1.f / 256.f);
    float var = q * (1.f / 256.f) - mu * mu;
    mu_s[tid] = mu;
    rs_s[tid] = rsqrtf(var + 1e-5f);
  }
  __syncthreads();
  unsigned short* zb = znbf + (size_t)(b * 256) * 1024 + l0;
  for (int rep = 0; rep < 16; rep++) {
    int idx = rep * 256 + tid;
    int h = idx >> 4;
    int l4 = (idx & 15) * 4;
    float gg = g[i * 256 + h], bb2 = bta[i * 256 + h];
    float o0 = (bf2f(tile[l4][h])     - mu_s[l4])     * rs_s[l4]     * gg + bb2;
    float o1 = (bf2f(tile[l4 + 1][h]) - mu_s[l4 + 1]) * rs_s[l4 + 1] * gg + bb2;
    float o2 = (bf2f(tile[l4 + 2][h]) - mu_s[l4 + 2]) * rs_s[l4 + 2] * gg + bb2;
    float o3 = (bf2f(tile[l4 + 3][h]) - mu_s[l4 + 3]) * rs_s[l4 + 3] * gg + bb2;
    ushort4 o4 = make_ushort4((unsigned short)f2bf(o0), (unsigned short)f2bf(o1),
                              (unsigned short)f2bf(o2), (unsigned short)f2bf(o3));
    *reinterpret_cast<ushort4*>(zb + (size_t)h * 1024 + l4) = o4;
  }
}

// ---------------- FUSED S4: panels built ONCE per h; bq-loop over 2 batch-groups ----------------
// Grid 256 (one block per h), 8 waves, one batch per wave per pass. No barriers in the loop:
// Bp/Blds are read-only after build; Sw is wave-private (aliases the dead Psb staging region).
// Tables computed inline per-j per-pass (R8 lesson: no long fp32 live ranges across MFMA).
__global__ __launch_bounds__(512, 1) void k_s4(
    const unsigned short* __restrict__ znbf, const unsigned short* __restrict__ Ptb,
    const float* __restrict__ wtab, const float* __restrict__ wTtab, const float* __restrict__ dCtab,
    const float* __restrict__ Ktap, const float* __restrict__ Dp,
    unsigned short* __restrict__ ygbf, int i) {
  int h = blockIdx.x;
  int tid = threadIdx.x;
  __shared__ unsigned short Bp[256 * 72];     // 36864 B  bloc B-panel [col][t]
  __shared__ unsigned short Blds[64 * 344];   // 44032 B  apply B-panel [t][k]
  __shared__ unsigned short SwPsb[34816];     // 69632 B  Psb[64][132] during build; Sw[8][2][16][136] after
  __shared__ float k0s[64], k1s[64];

  if (tid < 64) k0s[tid] = Ktap[h * 64 + tid];
  else if (tid < 128) k1s[tid - 64] = Ktap[16384 + h * 64 + (tid - 64)];

  // stage Psb <- Ptb[h] (bf16 copy, pitch 132)
  {
    const unsigned short* src = Ptb + (size_t)h * 8192;
    #pragma unroll
    for (int rep = 0; rep < 4; rep++) {
      int idx4 = (rep * 512 + tid) * 4;  // 8192 ushorts
      int t = idx4 >> 7, k = idx4 & 127;
      ushort4 v = *reinterpret_cast<const ushort4*>(src + idx4);
      *reinterpret_cast<ushort4*>(&SwPsb[t * 132 + k]) = v;
    }
  }
  __syncthreads();
  // build Bp[col][t] (col = dir*128 + comp*64 + n) AND Blds[t][k] from Psb
  {
    int t = tid & 63;
    int colblk = tid >> 6;
    #pragma unroll
    for (int cc = 0; cc < 32; cc++) {
      int col = colblk * 32 + cc;
      int n = col & 63, comp = (col >> 6) & 1, dir = col >> 7;
      int k = 2 * n + comp;
      unsigned short v = dir ? SwPsb[t * 132 + k] : SwPsb[(63 - t) * 132 + k];
      if (comp) v ^= 0x8000u;  // stored -im -> +im
      Bp[col * 72 + t] = v;
    }
    int trow = tid >> 6, klane = tid & 63;
    #pragma unroll
    for (int ti = 0; ti < 8; ti++) {
      int t2 = ti * 8 + trow;
      #pragma unroll
      for (int kc = 0; kc < 5; kc++) {
        int k = kc * 64 + klane;
        unsigned short v;
        if (kc < 2)      v = SwPsb[t2 * 132 + k];
        else if (kc < 4) v = SwPsb[(63 - t2) * 132 + (k - 128)];
        else {
          int tp = klane;
          float f = (t2 >= tp) ? k0s[t2 - tp] : k1s[tp - t2 - 1];
          v = (unsigned short)f2bf(f);
        }
        Blds[t2 * 344 + k] = v;
      }
    }
  }
  __syncthreads();  // builds done; Psb region now free for Sw

  int wid = tid >> 6, lane = tid & 63;
  int c = lane & 15, kq = lane >> 4;
  unsigned short* swf = &SwPsb[(wid * 2 + 0) * 2176];
  unsigned short* swb = &SwPsb[(wid * 2 + 1) * 2176];
  const int gib = (i * 256 + h) * 64;
  float dp = Dp[i * 256 + h];

  for (int bq = 0; bq < 2; bq++) {
    int b = bq * 8 + wid;
    const unsigned short* pzn = znbf + ((size_t)(b * 256 + h)) * 1024 + c * 64 + kq * 8;
    bf16x8 af0 = *reinterpret_cast<const bf16x8*>(pzn);
    bf16x8 af1 = *reinterpret_cast<const bf16x8*>(pzn + 32);

    f32x4 acc[16];
    #pragma unroll
    for (int nt = 0; nt < 16; nt++) acc[nt] = (f32x4){0.f, 0.f, 0.f, 0.f};
    #pragma unroll
    for (int nt = 0; nt < 16; nt++) {
      bf16x8 b0 = *reinterpret_cast<const bf16x8*>(&Bp[(nt * 16 + c) * 72 + kq * 8]);
      acc[nt] = __builtin_amdgcn_mfma_f32_16x16x32_bf16(af0, b0, acc[nt], 0, 0, 0);
    }
    #pragma unroll
    for (int nt = 0; nt < 16; nt++) {
      bf16x8 b1 = *reinterpret_cast<const bf16x8*>(&Bp[(nt * 16 + c) * 72 + 32 + kq * 8]);
      acc[nt] = __builtin_amdgcn_mfma_f32_16x16x32_bf16(af1, b1, acc[nt], 0, 0, 0);
    }

    // ---- register scan -> S' into wave-private Sw (tables inline per j) ----
    #pragma unroll
    for (int j = 0; j < 4; j++) {
      int n = j * 16 + c;
      int gi = gib + n;
      float wTr = wTtab[gi * 2], wTi = wTtab[gi * 2 + 1];
      float w2r = wTr * wTr - wTi * wTi, w2i = 2.f * wTr * wTi;
      float w4r = w2r * w2r - w2i * w2i, w4i = 2.f * w2r * w2i;
      float w8r = w4r * w4r - w4i * w4i, w8i = 2.f * w4r * w4i;
      float wr = wtab[gi * 2], wi = wtab[gi * 2 + 1];
      float d0r = dCtab[((size_t)(i * 2 + 0) * 256 + h) * 128 + 2 * n];
      float d0i = dCtab[((size_t)(i * 2 + 0) * 256 + h) * 128 + 2 * n + 1];
      float d1r = dCtab[((size_t)(i * 2 + 1) * 256 + h) * 128 + 2 * n];
      float d1i = dCtab[((size_t)(i * 2 + 1) * 256 + h) * 128 + 2 * n + 1];
      float mfr = 2.f * (d0r * wr - d0i * wi), mfi = 2.f * (d0r * wi + d0i * wr);
      float mbr = 2.f * d1r, mbi = 2.f * d1i;

      // forward
      {
        float er = 0.f, ei = 0.f, entr[4], enti[4];
        #pragma unroll
        for (int r = 0; r < 4; r++) {
          entr[r] = er; enti[r] = ei;
          float br = acc[j][r], bi = acc[j + 4][r];
          float t0 = er * wTr - ei * wTi + br;
          ei = er * wTi + ei * wTr + bi; er = t0;
        }
        float Gr = er, Gi = ei;
        float sr = __shfl_up(Gr, 16), si = __shfl_up(Gi, 16);
        if (kq >= 1) { Gr += sr * w4r - si * w4i; Gi += sr * w4i + si * w4r; }
        sr = __shfl_up(Gr, 32); si = __shfl_up(Gi, 32);
        if (kq >= 2) { Gr += sr * w8r - si * w8i; Gi += sr * w8i + si * w8r; }
        float Sgr = __shfl_up(Gr, 16), Sgi = __shfl_up(Gi, 16);
        if (kq == 0) { Sgr = 0.f; Sgi = 0.f; }
        float pr = 1.f, pi = 0.f;
        #pragma unroll
        for (int r = 0; r < 4; r++) {
          float scr = pr * Sgr - pi * Sgi + entr[r];
          float sci = pr * Sgi + pi * Sgr + enti[r];
          float opr = mfr * scr - mfi * sci;
          float opi = mfr * sci + mfi * scr;
          *reinterpret_cast<ushort2*>(swf + (kq * 4 + r) * 136 + 2 * n) =
              make_ushort2((unsigned short)f2bf(opr), (unsigned short)f2bf(opi));
          float t0 = pr * wTr - pi * wTi; pi = pr * wTi + pi * wTr; pr = t0;
        }
      }
      // backward
      {
        float er = 0.f, ei = 0.f, entr[4], enti[4];
        #pragma unroll
        for (int rr = 0; rr < 4; rr++) {
          int r = 3 - rr;
          entr[r] = er; enti[r] = ei;
          float br = acc[8 + j][r], bi = acc[12 + j][r];
          float t0 = er * wTr - ei * wTi + br;
          ei = er * wTi + ei * wTr + bi; er = t0;
        }
        float Gr = er, Gi = ei;
        float sr = __shfl_down(Gr, 16), si = __shfl_down(Gi, 16);
        if (kq <= 2) { Gr += sr * w4r - si * w4i; Gi += sr * w4i + si * w4r; }
        sr = __shfl_down(Gr, 32); si = __shfl_down(Gi, 32);
        if (kq <= 1) { Gr += sr * w8r - si * w8i; Gi += sr * w8i + si * w8r; }
        float Sgr = __shfl_down(Gr, 16), Sgi = __shfl_down(Gi, 16);
        if (kq == 3) { Sgr = 0.f; Sgi = 0.f; }
        float pr = 1.f, pi = 0.f;
        #pragma unroll
        for (int rr = 0; rr < 4; rr++) {
          int r = 3 - rr;  // wT^{3-r} = wT^{rr}
          float scr = pr * Sgr - pi * Sgi + entr[r];
          float sci = pr * Sgi + pi * Sgr + enti[r];
          float opr = mbr * scr - mbi * sci;
          float opi = mbr * sci + mbi * scr;
          *reinterpret_cast<ushort2*>(swb + (kq * 4 + r) * 136 + 2 * n) =
              make_ushort2((unsigned short)f2bf(opr), (unsigned short)f2bf(opi));
          float t0 = pr * wTr - pi * wTi; pi = pr * wTi + pi * wTr; pr = t0;
        }
      }
    }

    // ---- apply: C[chunk=c][t] over K=320 (Sw wave-private; in-wave ordering suffices) ----
    f32x4 acc2[4];
    #pragma unroll
    for (int nt = 0; nt < 4; nt++) acc2[nt] = (f32x4){0.f, 0.f, 0.f, 0.f};
    #pragma unroll
    for (int ks = 0; ks < 10; ks++) {
      bf16x8 af;
      if (ks < 4)       af = *reinterpret_cast<const bf16x8*>(swf + c * 136 + ks * 32 + kq * 8);
      else if (ks < 8)  af = *reinterpret_cast<const bf16x8*>(swb + c * 136 + (ks - 4) * 32 + kq * 8);
      else              af = *reinterpret_cast<const bf16x8*>(pzn + (ks - 8) * 32);
      #pragma unroll
      for (int nt = 0; nt < 4; nt++) {
        bf16x8 bfv = *reinterpret_cast<const bf16x8*>(&Blds[(nt * 16 + c) * 344 + ks * 32 + kq * 8]);
        acc2[nt] = __builtin_amdgcn_mfma_f32_16x16x32_bf16(af, bfv, acc2[nt], 0, 0, 0);
      }
    }

    size_t obase = (size_t)(b * 256 + h) * 1024;
    #pragma unroll
    for (int nt = 0; nt < 4; nt++) {
      #pragma unroll
      for (int r = 0; r < 4; r++) {
        int m = kq * 4 + r;
        int t = nt * 16 + c;
        size_t idx = obase + (size_t)m * 64 + t;
        float z = bf2f(znbf[idx]);
        float v = fmaf(z, dp, acc2[nt][r]);
        ygbf[idx] = (unsigned short)f2bf(gelu_f(v));
      }
    }
  }
}

// ---------------- MFMA GEMM over [B,H,L]: C[o,l] = sum_k W[o,k] * act[k,l] ----------------
// EPI 0 (GATE): u = acc + bias1[o] + aux1(x,bf16) + aux2(tt,f32) -> gate -> outb bf16
// EPI 1 (RES):  o<256: uio1(x,bf16) += ...; o>=256: uio2(skips,bf16) += ...
// EPI 4 (RES0): same but uio2 written (first block)
// EPI 2 (RELU): outb = bf16 relu(acc + bias1)
template <int EPI>
__global__ __launch_bounds__(256) void k_gemm(
    const unsigned short* __restrict__ Wbf, const float* __restrict__ bias1, const float* __restrict__ bias2,
    const unsigned short* __restrict__ act, unsigned short* __restrict__ uio1, unsigned short* __restrict__ uio2,
    unsigned short* __restrict__ outb, const unsigned short* __restrict__ aux1, const float* __restrict__ aux2) {
  int lt = blockIdx.x, ot = blockIdx.y, b = blockIdx.z;
  int tid = threadIdx.x;
  int l0 = lt * 128, o0 = ot * 64;
  __shared__ unsigned short Alds[128 * 40];  // [l][k] bf16, granule-rotated

  int wid = tid >> 6, lane = tid & 63;
  int wo = wid >> 1, wl = wid & 1;
  int c = lane & 15, kq = lane >> 4;

  int kq4 = tid >> 5;   // 0..7 -> k = kq4*4
  int lq = tid & 31;    // l = lq*4 + j
  const unsigned short* actb = act + (size_t)(b * 256) * 1024 + l0 + lq * 4;

  f32x4 acc[2][4];
  #pragma unroll
  for (int mo = 0; mo < 2; mo++)
    #pragma unroll
    for (int nl = 0; nl < 4; nl++) acc[mo][nl] = (f32x4){0.f, 0.f, 0.f, 0.f};

  ushort4 m0, m1, m2, m3;
  {
    const unsigned short* p = actb + (size_t)(kq4 * 4) * 1024;
    m0 = *reinterpret_cast<const ushort4*>(p);
    m1 = *reinterpret_cast<const ushort4*>(p + 1024);
    m2 = *reinterpret_cast<const ushort4*>(p + 2048);
    m3 = *reinterpret_cast<const ushort4*>(p + 3072);
  }

  for (int kc = 0; kc < 256; kc += 32) {
    {
      int g0 = kq4 >> 1, hh = (kq4 & 1) * 4;
      int rot = (g0 + lq) & 3;
      unsigned short* wp = &Alds[(lq * 4) * 40 + rot * 8 + hh];
      ushort4 w;
      w = make_ushort4(m0.x, m1.x, m2.x, m3.x); *reinterpret_cast<ushort4*>(wp) = w;
      w = make_ushort4(m0.y, m1.y, m2.y, m3.y); *reinterpret_cast<ushort4*>(wp + 40) = w;
      w = make_ushort4(m0.z, m1.z, m2.z, m3.z); *reinterpret_cast<ushort4*>(wp + 80) = w;
      w = make_ushort4(m0.w, m1.w, m2.w, m3.w); *reinterpret_cast<ushort4*>(wp + 120) = w;
    }
    __syncthreads();
    {
      int kcn = (kc + 32) & 255;
      const unsigned short* p = actb + (size_t)(kcn + kq4 * 4) * 1024;
      m0 = *reinterpret_cast<const ushort4*>(p);
      m1 = *reinterpret_cast<const ushort4*>(p + 1024);
      m2 = *reinterpret_cast<const ushort4*>(p + 2048);
      m3 = *reinterpret_cast<const ushort4*>(p + 3072);
    }
    bf16x8 af[2];
    #pragma unroll
    for (int mo = 0; mo < 2; mo++) {
      const unsigned short* wp = Wbf + (size_t)(o0 + wo * 32 + mo * 16 + c) * 256 + kc + kq * 8;
      af[mo] = *reinterpret_cast<const bf16x8*>(wp);
    }
    bf16x8 bfr[4];
    #pragma unroll
    for (int nl = 0; nl < 4; nl++) {
      int l = wl * 64 + nl * 16 + c;
      int rot = (kq + (l >> 2)) & 3;
      bfr[nl] = *reinterpret_cast<const bf16x8*>(&Alds[l * 40 + rot * 8]);
    }
    #pragma unroll
    for (int mo = 0; mo < 2; mo++)
      #pragma unroll
      for (int nl = 0; nl < 4; nl++)
        acc[mo][nl] = __builtin_amdgcn_mfma_f32_16x16x32_bf16(af[mo], bfr[nl], acc[mo][nl], 0, 0, 0);
    __syncthreads();
  }

  #pragma unroll
  for (int mo = 0; mo < 2; mo++) {
    #pragma unroll
    for (int nl = 0; nl < 4; nl++) {
      #pragma unroll
      for (int r = 0; r < 4; r++) {
        float a = acc[mo][nl][r];
        int o = o0 + wo * 32 + mo * 16 + kq * 4 + r;
        int l = l0 + wl * 64 + nl * 16 + c;
        if constexpr (EPI == 0) {
          size_t id = ((size_t)(b * 256 + o)) * 1024 + l;
          float u = a + bias1[o] + bf2f(aux1[id]) + aux2[b * 256 + o];
          float t = __expf(fminf(-u, 80.f));
          float gg = (1.f - t) / (1.f + t * t);
          outb[id] = (unsigned short)f2bf(gg);
        } else if constexpr (EPI == 1 || EPI == 4) {
          if (o < 256) {
            size_t id = ((size_t)(b * 256 + o)) * 1024 + l;
            uio1[id] = (unsigned short)f2bf(bf2f(uio1[id]) + a + bias1[o]);
          } else {
            int o2 = o - 256;
            size_t id = ((size_t)(b * 256 + o2)) * 1024 + l;
            if constexpr (EPI == 4) uio2[id] = (unsigned short)f2bf(a + bias2[o2]);
            else                    uio2[id] = (unsigned short)f2bf(bf2f(uio2[id]) + a + bias2[o2]);
          }
        } else {
          size_t id = ((size_t)(b * 256 + o)) * 1024 + l;
          outb[id] = (unsigned short)f2bf(fmaxf(a + bias1[o], 0.f));
        }
      }
    }
  }
}

// ---------------- final: out[b,l,d] = h1[b,:,l]@Wo2 + bo2 + input (h1 bf16) ----------------
__global__ __launch_bounds__(256) void k_out(
    const unsigned short* __restrict__ h1, const float* __restrict__ Wo2, const float* __restrict__ bo2,
    const float* __restrict__ inp, float* __restrict__ outp) {
  int lt = blockIdx.x, b = blockIdx.y, tid = threadIdx.x;
  __shared__ float sa[32][132];
  __shared__ float sw2[32][68];
  int l0 = lt * 128;
  float acc[4][8];
  #pragma unroll
  for (int r = 0; r < 4; r++)
    #pragma unroll
    for (int c2 = 0; c2 < 8; c2++) acc[r][c2] = 0.f;
  int df = (tid & 7) * 8;
  int lf = (tid >> 3) * 4;
  for (int kc = 0; kc < 256; kc += 32) {
    for (int rep = 0; rep < 4; rep++) {
      int idx = rep * 256 + tid;
      int kk = idx >> 5;
      int l4 = (idx & 31) * 4;
      ushort4 v = *reinterpret_cast<const ushort4*>(h1 + (size_t)(b * 256 + kc + kk) * 1024 + l0 + l4);
      sa[kk][l4] = bf2f(v.x); sa[kk][l4 + 1] = bf2f(v.y);
      sa[kk][l4 + 2] = bf2f(v.z); sa[kk][l4 + 3] = bf2f(v.w);
    }
    for (int rep = 0; rep < 8; rep++) {
      int idx = rep * 256 + tid;
      int kk = idx >> 6, d = idx & 63;
      sw2[kk][d] = Wo2[(size_t)(kc + kk) * 64 + d];
    }
    __syncthreads();
    for (int kk = 0; kk < 32; kk++) {
      float4 av = *reinterpret_cast<const float4*>(&sa[kk][lf]);
      float4 w1 = *reinterpret_cast<const float4*>(&sw2[kk][df]);
      float4 w2 = *reinterpret_cast<const float4*>(&sw2[kk][df + 4]);
      float avv[4] = {av.x, av.y, av.z, av.w};
      float wv[8] = {w1.x, w1.y, w1.z, w1.w, w2.x, w2.y, w2.z, w2.w};
      #pragma unroll
      for (int r = 0; r < 4; r++)
        #pragma unroll
        for (int c2 = 0; c2 < 8; c2++) acc[r][c2] = fmaf(avv[r], wv[c2], acc[r][c2]);
    }
    __syncthreads();
  }
  float bv[8];
  #pragma unroll
  for (int c2 = 0; c2 < 8; c2++) bv[c2] = bo2[df + c2];
  #pragma unroll
  for (int r = 0; r < 4; r++) {
    size_t base = (size_t)(b * 1024 + l0 + lf + r) * 64 + df;
    float4 i1 = *reinterpret_cast<const float4*>(inp + base);
    float4 i2 = *reinterpret_cast<const float4*>(inp + base + 4);
    float4 o1 = make_float4(acc[r][0] + bv[0] + i1.x, acc[r][1] + bv[1] + i1.y,
                            acc[r][2] + bv[2] + i1.z, acc[r][3] + bv[3] + i1.w);
    float4 o2 = make_float4(acc[r][4] + bv[4] + i2.x, acc[r][5] + bv[5] + i2.y,
                            acc[r][6] + bv[6] + i2.z, acc[r][7] + bv[7] + i2.w);
    *reinterpret_cast<float4*>(outp + base) = o1;
    *reinterpret_cast<float4*>(outp + base + 4) = o2;
  }
}

extern "C" void kernel_launch(void* const* d_in, const int* in_sizes, int n_in,
                              void* d_out, int out_size, void* d_ws, size_t ws_size,
                              hipStream_t stream) {
  const float* input   = (const float*)d_in[0];
  const float* t       = (const float*)d_in[1];
  const float* W_in    = (const float*)d_in[2];
  const float* b_in    = (const float*)d_in[3];
  const float* Wt1     = (const float*)d_in[4];
  const float* bt1     = (const float*)d_in[5];
  const float* Wt2     = (const float*)d_in[6];
  const float* bt2     = (const float*)d_in[7];
  const float* ln_g    = (const float*)d_in[8];
  const float* ln_b    = (const float*)d_in[9];
  const float* log_dt  = (const float*)d_in[10];
  const float* A_log_re= (const float*)d_in[11];
  const float* A_im    = (const float*)d_in[12];
  const float* C_re    = (const float*)d_in[13];
  const float* C_im    = (const float*)d_in[14];
  const float* Dp      = (const float*)d_in[15];
  const float* s4W     = (const float*)d_in[16];
  const float* s4b     = (const float*)d_in[17];
  const float* tW      = (const float*)d_in[18];
  const float* tb      = (const float*)d_in[19];
  const float* c1W     = (const float*)d_in[20];
  const float* c1b     = (const float*)d_in[21];
  const float* c2W     = (const float*)d_in[22];
  const float* c2b     = (const float*)d_in[23];
  const float* Wo1     = (const float*)d_in[24];
  const float* bo1     = (const float*)d_in[25];
  const float* Wo2     = (const float*)d_in[26];
  const float* bo2     = (const float*)d_in[27];

  float* ws = (float*)d_ws;
  size_t off = 0;
  float* xbuf   = ws + off; off += 4194304;   // bf16 x in low half
  float* znbuf  = ws + off; off += 4194304;   // bf16 zn in low half (after loop: h1 bf16)
  float* ygbuf  = ws + off; off += 4194304;   // [0,2M): yg_bf; [2M,4M): g_bf
  float* skbuf  = ws + off; off += 4194304;   // bf16 skips in low half
  float* tv     = ws + off; off += 4096;
  float* tt_all = ws + off; off += 24576;
  float* wtab   = ws + off; off += 196608;
  float* wTtab  = ws + off; off += 196608;
  float* dCtab  = ws + off; off += 393216;
  float* Ptbuf  = ws + off; off += 6291456;   // bf16 [6][H][64][128]
  float* Ktap   = ws + off; off += 196608;    // [6][2][H][64]
  unsigned short* s4Wbf  = (unsigned short*)(ws + off); off += 196608;
  unsigned short* c12Wbf = (unsigned short*)(ws + off); off += 393216;
  unsigned short* Wo1T   = (unsigned short*)(ws + off); off += 32768;

  unsigned short* xbf     = (unsigned short*)xbuf;
  unsigned short* znbf    = (unsigned short*)znbuf;
  unsigned short* ygbf    = (unsigned short*)ygbuf;
  unsigned short* gbf     = (unsigned short*)(ygbuf + 2097152);
  unsigned short* skipsbf = (unsigned short*)skbuf;
  unsigned short* Ptb     = (unsigned short*)Ptbuf;
  unsigned short* h1bf    = (unsigned short*)znbuf;

  k_temb<<<16, 256, 0, stream>>>(t, Wt1, bt1, Wt2, bt2, tv);
  k_tt<<<dim3(6, 16), 256, 0, stream>>>(tv, tW, tb, tt_all);
  k_in<<<dim3(16, 16), 256, 0, stream>>>(input, W_in, b_in, xbf);
  k_tab<<<384, 256, 0, stream>>>(log_dt, A_log_re, A_im, C_re, C_im, wtab, wTtab, dCtab);
  k_prep<<<4864, 256, 0, stream>>>(s4W, c1W, c2W, Wo1, s4Wbf, c12Wbf, Wo1T);
  k_pcar<<<384, 256, 0, stream>>>(wtab, Ptb);
  k_ktap<<<768, 256, 0, stream>>>(dCtab, Ptb, Ktap);

  for (int i = 0; i < 6; i++) {
    k_ln<<<dim3(16, 16), 256, 0, stream>>>(xbf, tt_all, ln_g, ln_b, znbf, i);
    k_s4<<<256, 512, 0, stream>>>(znbf, Ptb + (size_t)i * 2097152, wtab, wTtab, dCtab,
                                  Ktap + (size_t)i * 32768, Dp, ygbf, i);
    // g_bf = gate(s4W@yg + s4b + x + tt)
    k_gemm<0><<<dim3(8, 4, 16), 256, 0, stream>>>(s4Wbf + (size_t)i * 65536, s4b + i * 256, nullptr,
                                                  ygbf, nullptr, nullptr, gbf, xbf, tt_all + i * 4096);
    // x += c1W@g + c1b ; skips (+)= c2W@g + c2b  (fused, M=512)
    if (i == 0)
      k_gemm<4><<<dim3(8, 8, 16), 256, 0, stream>>>(c12Wbf, c1b, c2b, gbf, xbf, skipsbf,
                                                    nullptr, nullptr, nullptr);
    else
      k_gemm<1><<<dim3(8, 8, 16), 256, 0, stream>>>(c12Wbf + (size_t)i * 131072, c1b + i * 256,
                                                    c2b + i * 256, gbf, xbf, skipsbf,
                                                    nullptr, nullptr, nullptr);
  }
  // h1 = relu(Wo1^T @ skips + bo1)  (bf16 in/out)
  k_gemm<2><<<dim3(8, 4, 16), 256, 0, stream>>>(Wo1T, bo1, nullptr,
                                                skipsbf, nullptr, nullptr, h1bf, nullptr, nullptr);
  k_out<<<dim3(8, 16), 256, 0, stream>>>(h1bf, Wo2, bo2, input, (float*)d_out);
}

// Round 14
// 489.084 us; speedup vs baseline: 1.5709x; 1.5709x over previous
//
#include <hip/hip_runtime.h>
#include <math.h>

// Problem sizes
// B=16, L=1024, DIN=64, H=256, N=64, TEMB=128, NB=6; chunk T=64, C=16

typedef __attribute__((ext_vector_type(8))) short bf16x8;
typedef __attribute__((ext_vector_type(4))) float f32x4;

__device__ __forceinline__ short f2bf(float f) {
  unsigned u = __builtin_bit_cast(unsigned, f);
  unsigned r = (u + 0x7FFFu + ((u >> 16) & 1u)) >> 16;
  return (short)r;
}
__device__ __forceinline__ float bf2f(unsigned short v) {
  unsigned u = ((unsigned)v) << 16;
  return __builtin_bit_cast(float, u);
}
__device__ __forceinline__ float gelu_f(float v) {
  // tanh-form gelu via sigmoid: v * sigmoid(2*0.7978845608*(v + 0.044715 v^3)); max err ~3e-4
  float q = 1.5957691216f * v * fmaf(0.044715f, v * v, 1.f);
  return v / (1.f + __expf(-q));
}

// ---------------- t-embedding MLP:  tv[b,h] ----------------
__global__ __launch_bounds__(256) void k_temb(
    const float* __restrict__ t, const float* __restrict__ Wt1, const float* __restrict__ bt1,
    const float* __restrict__ Wt2, const float* __restrict__ bt2, float* __restrict__ tv) {
  int b = blockIdx.x, tid = threadIdx.x;
  __shared__ float emb[128];
  __shared__ float tv1[256];
  if (tid < 128) {
    int j = tid & 63;
    float f = expf(-logf(10000.f) / 63.f * (float)j);
    float a = t[b] * f;
    emb[tid] = (tid < 64) ? sinf(a) : cosf(a);
  }
  __syncthreads();
  float acc = bt1[tid];
  for (int k = 0; k < 128; k++) acc = fmaf(emb[k], Wt1[k * 256 + tid], acc);
  tv1[tid] = acc / (1.f + expf(-acc));
  __syncthreads();
  float acc2 = bt2[tid];
  for (int k = 0; k < 256; k++) acc2 = fmaf(tv1[k], Wt2[k * 256 + tid], acc2);
  tv[b * 256 + tid] = acc2 / (1.f + expf(-acc2));
}

// ---------------- tt_all[i,b,h] = tv[b]@tW[i] + tb[i] ----------------
__global__ __launch_bounds__(256) void k_tt(
    const float* __restrict__ tv, const float* __restrict__ tW, const float* __restrict__ tb,
    float* __restrict__ tt_all) {
  int i = blockIdx.x, b = blockIdx.y, h = threadIdx.x;
  __shared__ float s[256];
  s[h] = tv[b * 256 + h];
  __syncthreads();
  const float* W = tW + i * 256 * 256;
  float acc = tb[i * 256 + h];
  for (int k = 0; k < 256; k++) acc = fmaf(s[k], W[k * 256 + h], acc);
  tt_all[(i * 16 + b) * 256 + h] = acc;
}

// ---------------- input proj: xbf[b,h,l] = relu(input@W_in + b_in), transposed, bf16 ----------------
__global__ __launch_bounds__(256) void k_in(
    const float* __restrict__ inp, const float* __restrict__ W, const float* __restrict__ bias,
    unsigned short* __restrict__ xbf) {
  int lt = blockIdx.x, b = blockIdx.y, h = threadIdx.x;
  __shared__ float si[64][68];
  int l0 = lt * 64;
  for (int rep = 0; rep < 16; rep++) {
    int idx = rep * 256 + h;
    int l = idx >> 6, d = idx & 63;
    si[l][d] = inp[(size_t)(b * 1024 + l0 + l) * 64 + d];
  }
  float wc[64];
  #pragma unroll
  for (int d = 0; d < 64; d++) wc[d] = W[d * 256 + h];
  float bh = bias[h];
  __syncthreads();
  unsigned short* xp = xbf + (size_t)(b * 256 + h) * 1024 + l0;
  for (int l4 = 0; l4 < 16; l4++) {
    float op[4];
    #pragma unroll
    for (int j = 0; j < 4; j++) {
      int l = l4 * 4 + j;
      float a = bh;
      #pragma unroll
      for (int d4 = 0; d4 < 16; d4++) {
        float4 v = *reinterpret_cast<const float4*>(&si[l][d4 * 4]);
        a = fmaf(v.x, wc[d4 * 4 + 0], a);
        a = fmaf(v.y, wc[d4 * 4 + 1], a);
        a = fmaf(v.z, wc[d4 * 4 + 2], a);
        a = fmaf(v.w, wc[d4 * 4 + 3], a);
      }
      op[j] = fmaxf(a, 0.f);
    }
    ushort4 o = make_ushort4((unsigned short)f2bf(op[0]), (unsigned short)f2bf(op[1]),
                             (unsigned short)f2bf(op[2]), (unsigned short)f2bf(op[3]));
    *reinterpret_cast<ushort4*>(xp + l4 * 4) = o;
  }
}

// ---------------- per-mode tables: w, w^64, dC (all blocks) ----------------
__global__ __launch_bounds__(256) void k_tab(
    const float* __restrict__ log_dt, const float* __restrict__ A_log_re, const float* __restrict__ A_im,
    const float* __restrict__ C_re, const float* __restrict__ C_im,
    float* __restrict__ wtab, float* __restrict__ wTtab, float* __restrict__ dCtab) {
  int idx = blockIdx.x * 256 + threadIdx.x;  // over NB*H*N = 98304
  int i = idx / (256 * 64);
  int rem = idx % (256 * 64);
  int h = rem >> 6, n = rem & 63;
  float dt = expf(log_dt[i * 256 + h]);
  float Ar = -expf(A_log_re[idx]);
  float Ai = A_im[idx];
  float ar = dt * Ar, ai = dt * Ai;
  float ea = expf(ar);
  float wr = ea * cosf(ai), wi = ea * sinf(ai);
  float pr = wr, pi = wi;
  #pragma unroll
  for (int s = 0; s < 6; s++) { float nr = pr * pr - pi * pi; float ni = 2.f * pr * pi; pr = nr; pi = ni; }
  float den = Ar * Ar + Ai * Ai;
  float qr = ((wr - 1.f) * Ar + wi * Ai) / den;
  float qi = (wi * Ar - (wr - 1.f) * Ai) / den;
  wtab[idx * 2] = wr; wtab[idx * 2 + 1] = wi;
  wTtab[idx * 2] = pr; wTtab[idx * 2 + 1] = pi;
  #pragma unroll
  for (int s = 0; s < 2; s++) {
    float cr = C_re[((size_t)(i * 2 + s) * 256 + h) * 64 + n];
    float ci = C_im[((size_t)(i * 2 + s) * 256 + h) * 64 + n];
    dCtab[(((size_t)(i * 2 + s) * 256 + h) * 64 + n) * 2]     = cr * qr - ci * qi;
    dCtab[(((size_t)(i * 2 + s) * 256 + h) * 64 + n) * 2 + 1] = cr * qi + ci * qr;
  }
}

// ---------------- weight prep: bf16 conversions ----------------
__global__ __launch_bounds__(256) void k_prep(
    const float* __restrict__ s4W, const float* __restrict__ c1W, const float* __restrict__ c2W,
    const float* __restrict__ Wo1,
    unsigned short* __restrict__ s4Wbf, unsigned short* __restrict__ c12Wbf, unsigned short* __restrict__ Wo1T) {
  int idx = blockIdx.x * 256 + threadIdx.x;  // 4864*256 = 1245184
  if (idx < 393216) {
    s4Wbf[idx] = (unsigned short)f2bf(s4W[idx]);
  } else if (idx < 393216 + 786432) {
    int j = idx - 393216;
    int i = j / 131072, r = j % 131072;
    int o2 = r >> 8, k = r & 255;
    float v = (o2 < 256) ? c1W[(size_t)i * 65536 + o2 * 256 + k]
                         : c2W[(size_t)i * 65536 + (o2 - 256) * 256 + k];
    c12Wbf[j] = (unsigned short)f2bf(v);
  } else {
    int j = idx - 1179648;  // < 65536
    int o = j >> 8, k = j & 255;
    Wo1T[j] = (unsigned short)f2bf(Wo1[k * 256 + o]);
  }
}

// ---------------- Ptb[i][h][t][2n{+1}] = bf16 {Re, -Im}(w^t), all blocks ----------------
__global__ __launch_bounds__(256) void k_pcar(const float* __restrict__ wtab, unsigned short* __restrict__ Ptb) {
  int idx = blockIdx.x * 256 + threadIdx.x;  // i*16384 + h*64 + n, 98304
  int i = idx >> 14, h = (idx >> 6) & 255, n = idx & 63;
  float wr = wtab[idx * 2], wi = wtab[idx * 2 + 1];
  float pr = 1.f, pi = 0.f;
  unsigned short* base = Ptb + (size_t)i * 2097152 + (size_t)h * 8192 + 2 * n;
  for (int t = 0; t < 64; t++) {
    *reinterpret_cast<ushort2*>(base + t * 128) =
        make_ushort2((unsigned short)f2bf(pr), (unsigned short)f2bf(-pi));
    float nr2 = pr * wr - pi * wi, ni2 = pr * wi + pi * wr;
    pr = nr2; pi = ni2;
  }
}

// ---------------- Ktap_all[i][s][h][j] = 2 Re(sum_n dC_s w^j) ----------------
__global__ __launch_bounds__(256) void k_ktap(
    const float* __restrict__ dCtab, const unsigned short* __restrict__ Ptb, float* __restrict__ Ktap) {
  int idx = blockIdx.x * 256 + threadIdx.x;  // ((i*2+s)*256+h)*64+j, 196608
  int j = idx & 63;
  int h = (idx >> 6) & 255;
  int i = idx >> 15;
  const float* dc = dCtab + (size_t)(idx >> 6) * 128;
  const unsigned short* P = Ptb + (size_t)i * 2097152 + (size_t)h * 8192 + j * 128;
  float acc = 0.f;
  for (int q = 0; q < 32; q++) {
    float4 d = *reinterpret_cast<const float4*>(dc + q * 4);
    ushort4 p = *reinterpret_cast<const ushort4*>(P + q * 4);
    acc = fmaf(d.x, bf2f(p.x), fmaf(d.y, bf2f(p.y), fmaf(d.z, bf2f(p.z), fmaf(d.w, bf2f(p.w), acc))));
  }
  Ktap[idx] = 2.f * acc;
}

// ---------------- LayerNorm over H with +tt, xbf -> zn bf16 ----------------
__global__ __launch_bounds__(256) void k_ln(
    const unsigned short* __restrict__ xbf, const float* __restrict__ tt_all,
    const float* __restrict__ g, const float* __restrict__ bta, unsigned short* __restrict__ znbf, int i) {
  int ct = blockIdx.x, b = blockIdx.y, tid = threadIdx.x;
  __shared__ unsigned short tile[64][266];
  __shared__ float stt[256];
  __shared__ float red[8][64];
  __shared__ float mu_s[64], rs_s[64];
  stt[tid] = tt_all[(i * 16 + b) * 256 + tid];
  __syncthreads();
  int l0 = ct * 64;
  const unsigned short* xb = xbf + (size_t)(b * 256) * 1024 + l0;
  for (int rep = 0; rep < 16; rep++) {
    int idx = rep * 256 + tid;
    int h = idx >> 4;
    int l4 = (idx & 15) * 4;
    ushort4 v = *reinterpret_cast<const ushort4*>(xb + (size_t)h * 1024 + l4);
    float a = stt[h];
    tile[l4][h]     = (unsigned short)f2bf(bf2f(v.x) + a);
    tile[l4 + 1][h] = (unsigned short)f2bf(bf2f(v.y) + a);
    tile[l4 + 2][h] = (unsigned short)f2bf(bf2f(v.z) + a);
    tile[l4 + 3][h] = (unsigned short)f2bf(bf2f(v.w) + a);
  }
  __syncthreads();
  int l = tid & 63, part = tid >> 6;
  float s1 = 0.f, s2 = 0.f;
  for (int k2 = 0; k2 < 32; k2++) {
    ushort2 v2 = *reinterpret_cast<const ushort2*>(&tile[l][part * 64 + k2 * 2]);
    float a = bf2f(v2.x), bq = bf2f(v2.y);
    s1 += a + bq;
    s2 = fmaf(a, a, fmaf(bq, bq, s2));
  }
  red[part][l] = s1; red[4 + part][l] = s2;
  __syncthreads();
  if (tid < 64) {
    float a = red[0][tid] + red[1][tid] + red[2][tid] + red[3][tid];
    float q = red[4][tid] + red[5][tid] + red[6][tid] + red[7][tid];
    float mu = a * (1.f / 256.f);
    float var = q * (1.f / 256.f) - mu * mu;
    mu_s[tid] = mu;
    rs_s[tid] = rsqrtf(var + 1e-5f);
  }
  __syncthreads();
  unsigned short* zb = znbf + (size_t)(b * 256) * 1024 + l0;
  for (int rep = 0; rep < 16; rep++) {
    int idx = rep * 256 + tid;
    int h = idx >> 4;
    int l4 = (idx & 15) * 4;
    float gg = g[i * 256 + h], bb2 = bta[i * 256 + h];
    float o0 = (bf2f(tile[l4][h])     - mu_s[l4])     * rs_s[l4]     * gg + bb2;
    float o1 = (bf2f(tile[l4 + 1][h]) - mu_s[l4 + 1]) * rs_s[l4 + 1] * gg + bb2;
    float o2 = (bf2f(tile[l4 + 2][h]) - mu_s[l4 + 2]) * rs_s[l4 + 2] * gg + bb2;
    float o3 = (bf2f(tile[l4 + 3][h]) - mu_s[l4 + 3]) * rs_s[l4 + 3] * gg + bb2;
    ushort4 o4 = make_ushort4((unsigned short)f2bf(o0), (unsigned short)f2bf(o1),
                              (unsigned short)f2bf(o2), (unsigned short)f2bf(o3));
    *reinterpret_cast<ushort4*>(zb + (size_t)h * 1024 + l4) = o4;
  }
}

// ---------------- FUSED S4: bloc MFMA + in-wave scan + carry/Toeplitz MFMA + gelu ----------------
// Grid (256, 2): one block per (h, 8-batch group); one batch per wave. NO internal bq loop
// (R8/R13 lesson: loop-carried acc[16]+scan live ranges spill at the 128-VGPR budget).
__global__ __launch_bounds__(512, 1) void k_s4(
    const unsigned short* __restrict__ znbf, const unsigned short* __restrict__ Ptb,
    const float* __restrict__ wtab, const float* __restrict__ wTtab, const float* __restrict__ dCtab,
    const float* __restrict__ Ktap, const float* __restrict__ Dp,
    unsigned short* __restrict__ ygbf, int i) {
  int h = blockIdx.x;
  int tid = threadIdx.x;
  __shared__ unsigned short Psb[64 * 132];       // 16896 B  bf16 {re,-im}(w^t), pitch 132
  __shared__ unsigned short XR[22016];           // 44032 B: Bp[256][72] then Blds[64][344]
  __shared__ unsigned short Sw[34816];           // 69632 B  per-wave S' [8][2][16][136]
  __shared__ float k0s[64], k1s[64];

  if (tid < 64) k0s[tid] = Ktap[h * 64 + tid];
  else if (tid < 128) k1s[tid - 64] = Ktap[16384 + h * 64 + (tid - 64)];

  // stage Psb <- Ptb[h] (bf16 copy)
  {
    const unsigned short* src = Ptb + (size_t)h * 8192;
    #pragma unroll
    for (int rep = 0; rep < 4; rep++) {
      int idx4 = (rep * 512 + tid) * 4;  // 8192 ushorts
      int t = idx4 >> 7, k = idx4 & 127;
      ushort4 v = *reinterpret_cast<const ushort4*>(src + idx4);
      *reinterpret_cast<ushort4*>(&Psb[t * 132 + k]) = v;
    }
  }
  __syncthreads();
  // build Bp[col][t], col = dir*128 + comp*64 + n (comp-separated)
  {
    int t = tid & 63;
    int colblk = tid >> 6;
    #pragma unroll
    for (int cc = 0; cc < 32; cc++) {
      int col = colblk * 32 + cc;
      int n = col & 63, comp = (col >> 6) & 1, dir = col >> 7;
      int k = 2 * n + comp;
      unsigned short v = dir ? Psb[t * 132 + k] : Psb[(63 - t) * 132 + k];
      if (comp) v ^= 0x8000u;  // stored -im -> +im
      XR[col * 72 + t] = v;
    }
  }
  __syncthreads();

  int wid = tid >> 6, lane = tid & 63;
  int b = blockIdx.y * 8 + wid;          // one batch per wave
  int c = lane & 15, kq = lane >> 4;
  const unsigned short* pzn = znbf + ((size_t)(b * 256 + h)) * 1024 + c * 64 + kq * 8;

  bf16x8 af0 = *reinterpret_cast<const bf16x8*>(pzn);
  bf16x8 af1 = *reinterpret_cast<const bf16x8*>(pzn + 32);

  f32x4 acc[16];
  #pragma unroll
  for (int nt = 0; nt < 16; nt++) acc[nt] = (f32x4){0.f, 0.f, 0.f, 0.f};
  #pragma unroll
  for (int nt = 0; nt < 16; nt++) {
    bf16x8 b0 = *reinterpret_cast<const bf16x8*>(&XR[(nt * 16 + c) * 72 + kq * 8]);
    acc[nt] = __builtin_amdgcn_mfma_f32_16x16x32_bf16(af0, b0, acc[nt], 0, 0, 0);
  }
  #pragma unroll
  for (int nt = 0; nt < 16; nt++) {
    bf16x8 b1 = *reinterpret_cast<const bf16x8*>(&XR[(nt * 16 + c) * 72 + 32 + kq * 8]);
    acc[nt] = __builtin_amdgcn_mfma_f32_16x16x32_bf16(af1, b1, acc[nt], 0, 0, 0);
  }
  __syncthreads();  // Bp dead

  // rebuild XR as Blds[64][344]
  {
    int trow = tid >> 6, klane = tid & 63;
    #pragma unroll
    for (int ti = 0; ti < 8; ti++) {
      int t2 = ti * 8 + trow;
      #pragma unroll
      for (int kc = 0; kc < 5; kc++) {
        int k = kc * 64 + klane;
        unsigned short v;
        if (kc < 2)      v = Psb[t2 * 132 + k];
        else if (kc < 4) v = Psb[(63 - t2) * 132 + (k - 128)];
        else {
          int tp = klane;
          float f = (t2 >= tp) ? k0s[t2 - tp] : k1s[tp - t2 - 1];
          v = (unsigned short)f2bf(f);
        }
        XR[t2 * 344 + k] = v;
      }
    }
  }

  // ---- register scan -> S' into wave-private Sw (tables inline per j) ----
  unsigned short* swf = &Sw[(wid * 2 + 0) * 2176];
  unsigned short* swb = &Sw[(wid * 2 + 1) * 2176];
  const int gib = (i * 256 + h) * 64;
  #pragma unroll
  for (int j = 0; j < 4; j++) {
    int n = j * 16 + c;
    int gi = gib + n;
    float wTr = wTtab[gi * 2], wTi = wTtab[gi * 2 + 1];
    float w2r = wTr * wTr - wTi * wTi, w2i = 2.f * wTr * wTi;
    float w4r = w2r * w2r - w2i * w2i, w4i = 2.f * w2r * w2i;
    float w8r = w4r * w4r - w4i * w4i, w8i = 2.f * w4r * w4i;
    float wr = wtab[gi * 2], wi = wtab[gi * 2 + 1];
    float d0r = dCtab[((size_t)(i * 2 + 0) * 256 + h) * 128 + 2 * n];
    float d0i = dCtab[((size_t)(i * 2 + 0) * 256 + h) * 128 + 2 * n + 1];
    float d1r = dCtab[((size_t)(i * 2 + 1) * 256 + h) * 128 + 2 * n];
    float d1i = dCtab[((size_t)(i * 2 + 1) * 256 + h) * 128 + 2 * n + 1];
    float mfr = 2.f * (d0r * wr - d0i * wi), mfi = 2.f * (d0r * wi + d0i * wr);
    float mbr = 2.f * d1r, mbi = 2.f * d1i;

    // forward
    {
      float er = 0.f, ei = 0.f, entr[4], enti[4];
      #pragma unroll
      for (int r = 0; r < 4; r++) {
        entr[r] = er; enti[r] = ei;
        float br = acc[j][r], bi = acc[j + 4][r];
        float t0 = er * wTr - ei * wTi + br;
        ei = er * wTi + ei * wTr + bi; er = t0;
      }
      float Gr = er, Gi = ei;
      float sr = __shfl_up(Gr, 16), si = __shfl_up(Gi, 16);
      if (kq >= 1) { Gr += sr * w4r - si * w4i; Gi += sr * w4i + si * w4r; }
      sr = __shfl_up(Gr, 32); si = __shfl_up(Gi, 32);
      if (kq >= 2) { Gr += sr * w8r - si * w8i; Gi += sr * w8i + si * w8r; }
      float Sgr = __shfl_up(Gr, 16), Sgi = __shfl_up(Gi, 16);
      if (kq == 0) { Sgr = 0.f; Sgi = 0.f; }
      float pr = 1.f, pi = 0.f;
      #pragma unroll
      for (int r = 0; r < 4; r++) {
        float scr = pr * Sgr - pi * Sgi + entr[r];
        float sci = pr * Sgi + pi * Sgr + enti[r];
        float opr = mfr * scr - mfi * sci;
        float opi = mfr * sci + mfi * scr;
        *reinterpret_cast<ushort2*>(swf + (kq * 4 + r) * 136 + 2 * n) =
            make_ushort2((unsigned short)f2bf(opr), (unsigned short)f2bf(opi));
        float t0 = pr * wTr - pi * wTi; pi = pr * wTi + pi * wTr; pr = t0;
      }
    }
    // backward
    {
      float er = 0.f, ei = 0.f, entr[4], enti[4];
      #pragma unroll
      for (int rr = 0; rr < 4; rr++) {
        int r = 3 - rr;
        entr[r] = er; enti[r] = ei;
        float br = acc[8 + j][r], bi = acc[12 + j][r];
        float t0 = er * wTr - ei * wTi + br;
        ei = er * wTi + ei * wTr + bi; er = t0;
      }
      float Gr = er, Gi = ei;
      float sr = __shfl_down(Gr, 16), si = __shfl_down(Gi, 16);
      if (kq <= 2) { Gr += sr * w4r - si * w4i; Gi += sr * w4i + si * w4r; }
      sr = __shfl_down(Gr, 32); si = __shfl_down(Gi, 32);
      if (kq <= 1) { Gr += sr * w8r - si * w8i; Gi += sr * w8i + si * w8r; }
      float Sgr = __shfl_down(Gr, 16), Sgi = __shfl_down(Gi, 16);
      if (kq == 3) { Sgr = 0.f; Sgi = 0.f; }
      float pr = 1.f, pi = 0.f;
      #pragma unroll
      for (int rr = 0; rr < 4; rr++) {
        int r = 3 - rr;  // wT^{3-r} = wT^{rr}
        float scr = pr * Sgr - pi * Sgi + entr[r];
        float sci = pr * Sgi + pi * Sgr + enti[r];
        float opr = mbr * scr - mbi * sci;
        float opi = mbr * sci + mbi * scr;
        *reinterpret_cast<ushort2*>(swb + (kq * 4 + r) * 136 + 2 * n) =
            make_ushort2((unsigned short)f2bf(opr), (unsigned short)f2bf(opi));
        float t0 = pr * wTr - pi * wTi; pi = pr * wTi + pi * wTr; pr = t0;
      }
    }
  }
  __syncthreads();  // Blds complete; Sw drained

  // ---- apply: C[chunk=c][t] over K=320 ----
  f32x4 acc2[4];
  #pragma unroll
  for (int nt = 0; nt < 4; nt++) acc2[nt] = (f32x4){0.f, 0.f, 0.f, 0.f};
  #pragma unroll
  for (int ks = 0; ks < 10; ks++) {
    bf16x8 af;
    if (ks < 4)       af = *reinterpret_cast<const bf16x8*>(swf + c * 136 + ks * 32 + kq * 8);
    else if (ks < 8)  af = *reinterpret_cast<const bf16x8*>(swb + c * 136 + (ks - 4) * 32 + kq * 8);
    else              af = *reinterpret_cast<const bf16x8*>(pzn + (ks - 8) * 32);
    #pragma unroll
    for (int nt = 0; nt < 4; nt++) {
      bf16x8 bfv = *reinterpret_cast<const bf16x8*>(&XR[(nt * 16 + c) * 344 + ks * 32 + kq * 8]);
      acc2[nt] = __builtin_amdgcn_mfma_f32_16x16x32_bf16(af, bfv, acc2[nt], 0, 0, 0);
    }
  }

  float dp = Dp[i * 256 + h];
  size_t obase = (size_t)(b * 256 + h) * 1024;
  #pragma unroll
  for (int nt = 0; nt < 4; nt++) {
    #pragma unroll
    for (int r = 0; r < 4; r++) {
      int m = kq * 4 + r;
      int t = nt * 16 + c;
      size_t idx = obase + (size_t)m * 64 + t;
      float z = bf2f(znbf[idx]);
      float v = fmaf(z, dp, acc2[nt][r]);
      ygbf[idx] = (unsigned short)f2bf(gelu_f(v));
    }
  }
}

// ---------------- MFMA GEMM over [B,H,L]: C[o,l] = sum_k W[o,k] * act[k,l] ----------------
// EPI 0 (GATE): u = acc + bias1[o] + aux1(x,bf16) + aux2(tt,f32) -> gate -> outb bf16
// EPI 1 (RES):  o<256: uio1(x,bf16) += ...; o>=256: uio2(skips,bf16) += ...
// EPI 4 (RES0): same but uio2 written (first block)
// EPI 2 (RELU): outb = bf16 relu(acc + bias1)
template <int EPI>
__global__ __launch_bounds__(256) void k_gemm(
    const unsigned short* __restrict__ Wbf, const float* __restrict__ bias1, const float* __restrict__ bias2,
    const unsigned short* __restrict__ act, unsigned short* __restrict__ uio1, unsigned short* __restrict__ uio2,
    unsigned short* __restrict__ outb, const unsigned short* __restrict__ aux1, const float* __restrict__ aux2) {
  int lt = blockIdx.x, ot = blockIdx.y, b = blockIdx.z;
  int tid = threadIdx.x;
  int l0 = lt * 128, o0 = ot * 64;
  __shared__ unsigned short Alds[128 * 40];  // [l][k] bf16, granule-rotated

  int wid = tid >> 6, lane = tid & 63;
  int wo = wid >> 1, wl = wid & 1;
  int c = lane & 15, kq = lane >> 4;

  int kq4 = tid >> 5;   // 0..7 -> k = kq4*4
  int lq = tid & 31;    // l = lq*4 + j
  const unsigned short* actb = act + (size_t)(b * 256) * 1024 + l0 + lq * 4;

  f32x4 acc[2][4];
  #pragma unroll
  for (int mo = 0; mo < 2; mo++)
    #pragma unroll
    for (int nl = 0; nl < 4; nl++) acc[mo][nl] = (f32x4){0.f, 0.f, 0.f, 0.f};

  ushort4 m0, m1, m2, m3;
  {
    const unsigned short* p = actb + (size_t)(kq4 * 4) * 1024;
    m0 = *reinterpret_cast<const ushort4*>(p);
    m1 = *reinterpret_cast<const ushort4*>(p + 1024);
    m2 = *reinterpret_cast<const ushort4*>(p + 2048);
    m3 = *reinterpret_cast<const ushort4*>(p + 3072);
  }

  for (int kc = 0; kc < 256; kc += 32) {
    {
      int g0 = kq4 >> 1, hh = (kq4 & 1) * 4;
      int rot = (g0 + lq) & 3;
      unsigned short* wp = &Alds[(lq * 4) * 40 + rot * 8 + hh];
      ushort4 w;
      w = make_ushort4(m0.x, m1.x, m2.x, m3.x); *reinterpret_cast<ushort4*>(wp) = w;
      w = make_ushort4(m0.y, m1.y, m2.y, m3.y); *reinterpret_cast<ushort4*>(wp + 40) = w;
      w = make_ushort4(m0.z, m1.z, m2.z, m3.z); *reinterpret_cast<ushort4*>(wp + 80) = w;
      w = make_ushort4(m0.w, m1.w, m2.w, m3.w); *reinterpret_cast<ushort4*>(wp + 120) = w;
    }
    __syncthreads();
    {
      int kcn = (kc + 32) & 255;
      const unsigned short* p = actb + (size_t)(kcn + kq4 * 4) * 1024;
      m0 = *reinterpret_cast<const ushort4*>(p);
      m1 = *reinterpret_cast<const ushort4*>(p + 1024);
      m2 = *reinterpret_cast<const ushort4*>(p + 2048);
      m3 = *reinterpret_cast<const ushort4*>(p + 3072);
    }
    bf16x8 af[2];
    #pragma unroll
    for (int mo = 0; mo < 2; mo++) {
      const unsigned short* wp = Wbf + (size_t)(o0 + wo * 32 + mo * 16 + c) * 256 + kc + kq * 8;
      af[mo] = *reinterpret_cast<const bf16x8*>(wp);
    }
    bf16x8 bfr[4];
    #pragma unroll
    for (int nl = 0; nl < 4; nl++) {
      int l = wl * 64 + nl * 16 + c;
      int rot = (kq + (l >> 2)) & 3;
      bfr[nl] = *reinterpret_cast<const bf16x8*>(&Alds[l * 40 + rot * 8]);
    }
    #pragma unroll
    for (int mo = 0; mo < 2; mo++)
      #pragma unroll
      for (int nl = 0; nl < 4; nl++)
        acc[mo][nl] = __builtin_amdgcn_mfma_f32_16x16x32_bf16(af[mo], bfr[nl], acc[mo][nl], 0, 0, 0);
    __syncthreads();
  }

  #pragma unroll
  for (int mo = 0; mo < 2; mo++) {
    #pragma unroll
    for (int nl = 0; nl < 4; nl++) {
      #pragma unroll
      for (int r = 0; r < 4; r++) {
        float a = acc[mo][nl][r];
        int o = o0 + wo * 32 + mo * 16 + kq * 4 + r;
        int l = l0 + wl * 64 + nl * 16 + c;
        if constexpr (EPI == 0) {
          size_t id = ((size_t)(b * 256 + o)) * 1024 + l;
          float u = a + bias1[o] + bf2f(aux1[id]) + aux2[b * 256 + o];
          float t = __expf(fminf(-u, 80.f));
          float gg = (1.f - t) / (1.f + t * t);
          outb[id] = (unsigned short)f2bf(gg);
        } else if constexpr (EPI == 1 || EPI == 4) {
          if (o < 256) {
            size_t id = ((size_t)(b * 256 + o)) * 1024 + l;
            uio1[id] = (unsigned short)f2bf(bf2f(uio1[id]) + a + bias1[o]);
          } else {
            int o2 = o - 256;
            size_t id = ((size_t)(b * 256 + o2)) * 1024 + l;
            if constexpr (EPI == 4) uio2[id] = (unsigned short)f2bf(a + bias2[o2]);
            else                    uio2[id] = (unsigned short)f2bf(bf2f(uio2[id]) + a + bias2[o2]);
          }
        } else {
          size_t id = ((size_t)(b * 256 + o)) * 1024 + l;
          outb[id] = (unsigned short)f2bf(fmaxf(a + bias1[o], 0.f));
        }
      }
    }
  }
}

// ---------------- final: out[b,l,d] = h1[b,:,l]@Wo2 + bo2 + input (h1 bf16) ----------------
__global__ __launch_bounds__(256) void k_out(
    const unsigned short* __restrict__ h1, const float* __restrict__ Wo2, const float* __restrict__ bo2,
    const float* __restrict__ inp, float* __restrict__ outp) {
  int lt = blockIdx.x, b = blockIdx.y, tid = threadIdx.x;
  __shared__ float sa[32][132];
  __shared__ float sw2[32][68];
  int l0 = lt * 128;
  float acc[4][8];
  #pragma unroll
  for (int r = 0; r < 4; r++)
    #pragma unroll
    for (int c2 = 0; c2 < 8; c2++) acc[r][c2] = 0.f;
  int df = (tid & 7) * 8;
  int lf = (tid >> 3) * 4;
  for (int kc = 0; kc < 256; kc += 32) {
    for (int rep = 0; rep < 4; rep++) {
      int idx = rep * 256 + tid;
      int kk = idx >> 5;
      int l4 = (idx & 31) * 4;
      ushort4 v = *reinterpret_cast<const ushort4*>(h1 + (size_t)(b * 256 + kc + kk) * 1024 + l0 + l4);
      sa[kk][l4] = bf2f(v.x); sa[kk][l4 + 1] = bf2f(v.y);
      sa[kk][l4 + 2] = bf2f(v.z); sa[kk][l4 + 3] = bf2f(v.w);
    }
    for (int rep = 0; rep < 8; rep++) {
      int idx = rep * 256 + tid;
      int kk = idx >> 6, d = idx & 63;
      sw2[kk][d] = Wo2[(size_t)(kc + kk) * 64 + d];
    }
    __syncthreads();
    for (int kk = 0; kk < 32; kk++) {
      float4 av = *reinterpret_cast<const float4*>(&sa[kk][lf]);
      float4 w1 = *reinterpret_cast<const float4*>(&sw2[kk][df]);
      float4 w2 = *reinterpret_cast<const float4*>(&sw2[kk][df + 4]);
      float avv[4] = {av.x, av.y, av.z, av.w};
      float wv[8] = {w1.x, w1.y, w1.z, w1.w, w2.x, w2.y, w2.z, w2.w};
      #pragma unroll
      for (int r = 0; r < 4; r++)
        #pragma unroll
        for (int c2 = 0; c2 < 8; c2++) acc[r][c2] = fmaf(avv[r], wv[c2], acc[r][c2]);
    }
    __syncthreads();
  }
  float bv[8];
  #pragma unroll
  for (int c2 = 0; c2 < 8; c2++) bv[c2] = bo2[df + c2];
  #pragma unroll
  for (int r = 0; r < 4; r++) {
    size_t base = (size_t)(b * 1024 + l0 + lf + r) * 64 + df;
    float4 i1 = *reinterpret_cast<const float4*>(inp + base);
    float4 i2 = *reinterpret_cast<const float4*>(inp + base + 4);
    float4 o1 = make_float4(acc[r][0] + bv[0] + i1.x, acc[r][1] + bv[1] + i1.y,
                            acc[r][2] + bv[2] + i1.z, acc[r][3] + bv[3] + i1.w);
    float4 o2 = make_float4(acc[r][4] + bv[4] + i2.x, acc[r][5] + bv[5] + i2.y,
                            acc[r][6] + bv[6] + i2.z, acc[r][7] + bv[7] + i2.w);
    *reinterpret_cast<float4*>(outp + base) = o1;
    *reinterpret_cast<float4*>(outp + base + 4) = o2;
  }
}

extern "C" void kernel_launch(void* const* d_in, const int* in_sizes, int n_in,
                              void* d_out, int out_size, void* d_ws, size_t ws_size,
                              hipStream_t stream) {
  const float* input   = (const float*)d_in[0];
  const float* t       = (const float*)d_in[1];
  const float* W_in    = (const float*)d_in[2];
  const float* b_in    = (const float*)d_in[3];
  const float* Wt1     = (const float*)d_in[4];
  const float* bt1     = (const float*)d_in[5];
  const float* Wt2     = (const float*)d_in[6];
  const float* bt2     = (const float*)d_in[7];
  const float* ln_g    = (const float*)d_in[8];
  const float* ln_b    = (const float*)d_in[9];
  const float* log_dt  = (const float*)d_in[10];
  const float* A_log_re= (const float*)d_in[11];
  const float* A_im    = (const float*)d_in[12];
  const float* C_re    = (const float*)d_in[13];
  const float* C_im    = (const float*)d_in[14];
  const float* Dp      = (const float*)d_in[15];
  const float* s4W     = (const float*)d_in[16];
  const float* s4b     = (const float*)d_in[17];
  const float* tW      = (const float*)d_in[18];
  const float* tb      = (const float*)d_in[19];
  const float* c1W     = (const float*)d_in[20];
  const float* c1b     = (const float*)d_in[21];
  const float* c2W     = (const float*)d_in[22];
  const float* c2b     = (const float*)d_in[23];
  const float* Wo1     = (const float*)d_in[24];
  const float* bo1     = (const float*)d_in[25];
  const float* Wo2     = (const float*)d_in[26];
  const float* bo2     = (const float*)d_in[27];

  float* ws = (float*)d_ws;
  size_t off = 0;
  float* xbuf   = ws + off; off += 4194304;   // bf16 x in low half
  float* znbuf  = ws + off; off += 4194304;   // bf16 zn in low half (after loop: h1 bf16)
  float* ygbuf  = ws + off; off += 4194304;   // [0,2M): yg_bf; [2M,4M): g_bf
  float* skbuf  = ws + off; off += 4194304;   // bf16 skips in low half
  float* tv     = ws + off; off += 4096;
  float* tt_all = ws + off; off += 24576;
  float* wtab   = ws + off; off += 196608;
  float* wTtab  = ws + off; off += 196608;
  float* dCtab  = ws + off; off += 393216;
  float* Ptbuf  = ws + off; off += 6291456;   // bf16 [6][H][64][128]
  float* Ktap   = ws + off; off += 196608;    // [6][2][H][64]
  unsigned short* s4Wbf  = (unsigned short*)(ws + off); off += 196608;
  unsigned short* c12Wbf = (unsigned short*)(ws + off); off += 393216;
  unsigned short* Wo1T   = (unsigned short*)(ws + off); off += 32768;

  unsigned short* xbf     = (unsigned short*)xbuf;
  unsigned short* znbf    = (unsigned short*)znbuf;
  unsigned short* ygbf    = (unsigned short*)ygbuf;
  unsigned short* gbf     = (unsigned short*)(ygbuf + 2097152);
  unsigned short* skipsbf = (unsigned short*)skbuf;
  unsigned short* Ptb     = (unsigned short*)Ptbuf;
  unsigned short* h1bf    = (unsigned short*)znbuf;

  k_temb<<<16, 256, 0, stream>>>(t, Wt1, bt1, Wt2, bt2, tv);
  k_tt<<<dim3(6, 16), 256, 0, stream>>>(tv, tW, tb, tt_all);
  k_in<<<dim3(16, 16), 256, 0, stream>>>(input, W_in, b_in, xbf);
  k_tab<<<384, 256, 0, stream>>>(log_dt, A_log_re, A_im, C_re, C_im, wtab, wTtab, dCtab);
  k_prep<<<4864, 256, 0, stream>>>(s4W, c1W, c2W, Wo1, s4Wbf, c12Wbf, Wo1T);
  k_pcar<<<384, 256, 0, stream>>>(wtab, Ptb);
  k_ktap<<<768, 256, 0, stream>>>(dCtab, Ptb, Ktap);

  for (int i = 0; i < 6; i++) {
    k_ln<<<dim3(16, 16), 256, 0, stream>>>(xbf, tt_all, ln_g, ln_b, znbf, i);
    k_s4<<<dim3(256, 2), 512, 0, stream>>>(znbf, Ptb + (size_t)i * 2097152, wtab, wTtab, dCtab,
                                           Ktap + (size_t)i * 32768, Dp, ygbf, i);
    // g_bf = gate(s4W@yg + s4b + x + tt)
    k_gemm<0><<<dim3(8, 4, 16), 256, 0, stream>>>(s4Wbf + (size_t)i * 65536, s4b + i * 256, nullptr,
                                                  ygbf, nullptr, nullptr, gbf, xbf, tt_all + i * 4096);
    // x += c1W@g + c1b ; skips (+)= c2W@g + c2b  (fused, M=512)
    if (i == 0)
      k_gemm<4><<<dim3(8, 8, 16), 256, 0, stream>>>(c12Wbf, c1b, c2b, gbf, xbf, skipsbf,
                                                    nullptr, nullptr, nullptr);
    else
      k_gemm<1><<<dim3(8, 8, 16), 256, 0, stream>>>(c12Wbf + (size_t)i * 131072, c1b + i * 256,
                                                    c2b + i * 256, gbf, xbf, skipsbf,
                                                    nullptr, nullptr, nullptr);
  }
  // h1 = relu(Wo1^T @ skips + bo1)  (bf16 in/out)
  k_gemm<2><<<dim3(8, 4, 16), 256, 0, stream>>>(Wo1T, bo1, nullptr,
                                                skipsbf, nullptr, nullptr, h1bf, nullptr, nullptr);
  k_out<<<dim3(8, 16), 256, 0, stream>>>(h1bf, Wo2, bo2, input, (float*)d_out);
}